// Round 1
// baseline (87.825 us; speedup 1.0000x reference)
//
#include <hip/hip_runtime.h>
#include <math.h>

// ChamferLoss: B=64, N=2048, D4=4 (only components 1..3 used).
// out = sum_b sum_n 0.5*(min_m dist(p[b,n],q[b,m]) + min over the other dir)
//
// Pure VALU fp32 compute-bound: 536M pair evals * 7 ops ~ 48us floor.

constexpr int B_ = 64;
constexpr int N_ = 2048;
constexpr int BLOCK = 256;
constexpr int PPT = 2;                          // points per thread
constexpr int PTS_PER_BLK = BLOCK * PPT;        // 512
constexpr int BLKS_PER = N_ / PTS_PER_BLK;      // 4

__global__ __launch_bounds__(BLOCK) void chamfer_kernel(
    const float* __restrict__ p, const float* __restrict__ q,
    float* __restrict__ out)
{
    __shared__ float sx[N_];
    __shared__ float sy[N_];
    __shared__ float sz[N_];

    const int dir = blockIdx.z;        // 0: rows=p, cols=q ; 1: rows=q, cols=p
    const int b   = blockIdx.y;
    const float* rowBase = (dir == 0 ? p : q) + (size_t)b * N_ * 4;
    const float* colBase = (dir == 0 ? q : p) + (size_t)b * N_ * 4;

    // Stage the column cloud into LDS (SoA), dropping component 0.
    for (int i = threadIdx.x; i < N_; i += BLOCK) {
        float4 v = *(const float4*)(colBase + i * 4);
        sx[i] = v.y; sy[i] = v.z; sz[i] = v.w;
    }
    __syncthreads();

    // Per-thread row points in registers.
    float px[PPT], py[PPT], pz[PPT], mn[PPT];
    const int base = blockIdx.x * PTS_PER_BLK + threadIdx.x;
#pragma unroll
    for (int t = 0; t < PPT; ++t) {
        float4 v = *(const float4*)(rowBase + (size_t)(base + t * BLOCK) * 4);
        px[t] = v.y; py[t] = v.z; pz[t] = v.w;
        mn[t] = 3.4e38f;
    }

    // Sweep all column points; unroll x4 so LDS reads are ds_read_b128
    // broadcasts amortized over PPT register points.
    for (int m = 0; m < N_; m += 4) {
        float4 X = *(const float4*)&sx[m];
        float4 Y = *(const float4*)&sy[m];
        float4 Z = *(const float4*)&sz[m];
        float xs[4] = {X.x, X.y, X.z, X.w};
        float ys[4] = {Y.x, Y.y, Y.z, Y.w};
        float zs[4] = {Z.x, Z.y, Z.z, Z.w};
#pragma unroll
        for (int j = 0; j < 4; ++j) {
#pragma unroll
            for (int t = 0; t < PPT; ++t) {
                float dx = px[t] - xs[j];
                float dy = py[t] - ys[j];
                float dz = pz[t] - zs[j];
                float d  = fmaf(dx, dx, fmaf(dy, dy, dz * dz));
                mn[t] = fminf(mn[t], d);
            }
        }
    }

    // sqrt once per point (monotonic => min over dsq first).
    float local = 0.0f;
#pragma unroll
    for (int t = 0; t < PPT; ++t) local += sqrtf(mn[t] + 1e-16f);

    // Wave (64) reduce, then block reduce, one atomic per block.
    for (int off = 32; off > 0; off >>= 1)
        local += __shfl_down(local, off, 64);

    __shared__ float wsum[BLOCK / 64];
    if ((threadIdx.x & 63) == 0) wsum[threadIdx.x >> 6] = local;
    __syncthreads();
    if (threadIdx.x == 0) {
        float s = 0.0f;
#pragma unroll
        for (int w = 0; w < BLOCK / 64; ++w) s += wsum[w];
        atomicAdd(out, 0.5f * s);
    }
}

extern "C" void kernel_launch(void* const* d_in, const int* in_sizes, int n_in,
                              void* d_out, int out_size, void* d_ws, size_t ws_size,
                              hipStream_t stream) {
    const float* p = (const float*)d_in[0];
    const float* q = (const float*)d_in[1];
    float* out = (float*)d_out;

    hipMemsetAsync(out, 0, sizeof(float), stream);

    dim3 grid(BLKS_PER, B_, 2);
    chamfer_kernel<<<grid, BLOCK, 0, stream>>>(p, q, out);
}

// Round 2
// 59.720 us; speedup vs baseline: 1.4706x; 1.4706x over previous
//
#include <hip/hip_runtime.h>
#include <math.h>

// ChamferLoss: B=64, N=2048, D4=4 (only components 1..3 used).
//
// Per-pair min-proxy: val = (-2qx)*px + (-2qy)*py + (-2qz)*pz + |q|^2
//                     dsq = r + min_m(val),  r = |p|^2  (added after the min)
// -> 3 FMA/pair + 0.5 min3/pair = 3.5 VALU instrs/pair. Floor ~24us.

constexpr int B_ = 64;
constexpr int N_ = 2048;
constexpr int BLOCK = 256;
constexpr int PPT = 2;                          // row points per thread
constexpr int PTS_PER_BLK = BLOCK * PPT;        // 512
constexpr int BLKS_PER = N_ / PTS_PER_BLK;      // 4

__global__ __launch_bounds__(BLOCK) void chamfer_kernel(
    const float* __restrict__ p, const float* __restrict__ q,
    float* __restrict__ out)
{
    __shared__ float4 scol[N_];                 // (-2x, -2y, -2z, |q|^2)

    const int dir = blockIdx.z;        // 0: rows=p, cols=q ; 1: rows=q, cols=p
    const int b   = blockIdx.y;
    const float* rowBase = (dir == 0 ? p : q) + (size_t)b * N_ * 4;
    const float* colBase = (dir == 0 ? q : p) + (size_t)b * N_ * 4;

    // Stage the column cloud into LDS, preprocessed.
    for (int i = threadIdx.x; i < N_; i += BLOCK) {
        float4 v = *(const float4*)(colBase + i * 4);
        float cc = fmaf(v.y, v.y, fmaf(v.z, v.z, v.w * v.w));
        scol[i] = make_float4(-2.0f * v.y, -2.0f * v.z, -2.0f * v.w, cc);
    }
    __syncthreads();

    // Per-thread row points in registers (+ their squared norms).
    float px[PPT], py[PPT], pz[PPT], rr[PPT], mn[PPT];
    const int base = blockIdx.x * PTS_PER_BLK + threadIdx.x;
#pragma unroll
    for (int t = 0; t < PPT; ++t) {
        float4 v = *(const float4*)(rowBase + (size_t)(base + t * BLOCK) * 4);
        px[t] = v.y; py[t] = v.z; pz[t] = v.w;
        rr[t] = fmaf(v.y, v.y, fmaf(v.z, v.z, v.w * v.w));
        mn[t] = 3.4e38f;
    }

    // Sweep all columns; 4-col unroll. Each column: 1 ds_read_b128 broadcast,
    // then 3 FMA per (col,row) and one v_min3 per 2 cols per row.
    for (int m = 0; m < N_; m += 4) {
        float4 c0 = scol[m + 0];
        float4 c1 = scol[m + 1];
        float4 c2 = scol[m + 2];
        float4 c3 = scol[m + 3];
#pragma unroll
        for (int t = 0; t < PPT; ++t) {
            float v0 = fmaf(c0.x, px[t], fmaf(c0.y, py[t], fmaf(c0.z, pz[t], c0.w)));
            float v1 = fmaf(c1.x, px[t], fmaf(c1.y, py[t], fmaf(c1.z, pz[t], c1.w)));
            float v2 = fmaf(c2.x, px[t], fmaf(c2.y, py[t], fmaf(c2.z, pz[t], c2.w)));
            float v3 = fmaf(c3.x, px[t], fmaf(c3.y, py[t], fmaf(c3.z, pz[t], c3.w)));
            mn[t] = fminf(mn[t], fminf(v0, v1));   // -> v_min3_f32
            mn[t] = fminf(mn[t], fminf(v2, v3));   // -> v_min3_f32
        }
    }

    // dsq = r + min(val); sqrt once per row point.
    float local = 0.0f;
#pragma unroll
    for (int t = 0; t < PPT; ++t) {
        float dsq = rr[t] + mn[t];
        local += sqrtf(fmaxf(dsq, 0.0f) + 1e-16f);
    }

    // Wave (64) reduce, then block reduce, one atomic per block.
    for (int off = 32; off > 0; off >>= 1)
        local += __shfl_down(local, off, 64);

    __shared__ float wsum[BLOCK / 64];
    if ((threadIdx.x & 63) == 0) wsum[threadIdx.x >> 6] = local;
    __syncthreads();
    if (threadIdx.x == 0) {
        float s = 0.0f;
#pragma unroll
        for (int w = 0; w < BLOCK / 64; ++w) s += wsum[w];
        atomicAdd(out, 0.5f * s);
    }
}

extern "C" void kernel_launch(void* const* d_in, const int* in_sizes, int n_in,
                              void* d_out, int out_size, void* d_ws, size_t ws_size,
                              hipStream_t stream) {
    const float* p = (const float*)d_in[0];
    const float* q = (const float*)d_in[1];
    float* out = (float*)d_out;

    hipMemsetAsync(out, 0, sizeof(float), stream);

    dim3 grid(BLKS_PER, B_, 2);
    chamfer_kernel<<<grid, BLOCK, 0, stream>>>(p, q, out);
}

// Round 3
// 58.706 us; speedup vs baseline: 1.4960x; 1.0173x over previous
//
#include <hip/hip_runtime.h>
#include <math.h>

// ChamferLoss: B=64, N=2048, D4=4 (components 1..3).
// Two-phase: (1) per-(batch,dir) blocks sweep a 256-column chunk against all
// 2048 rows, tracking min over val = |q|^2 - 2 q.p in registers; cross-chunk
// combine via atomicMin on order-preserving uint keys. (2) key->float, add
// |p|^2, sqrt, reduce.

constexpr int B_ = 64;
constexpr int N_ = 2048;
constexpr int BLOCK = 256;
constexpr int PPT = 8;                     // rows per thread (8*256 = all rows)
constexpr int S_ = 8;                      // column chunks per (b,dir)
constexpr int CCH = N_ / S_;               // 256 columns per chunk

__device__ __forceinline__ unsigned int fkey(float f) {
    unsigned int u = __float_as_uint(f);
    return (u & 0x80000000u) ? ~u : (u | 0x80000000u);
}
__device__ __forceinline__ float funkey(unsigned int k) {
    unsigned int u = (k & 0x80000000u) ? (k ^ 0x80000000u) : ~k;
    return __uint_as_float(u);
}

__global__ __launch_bounds__(BLOCK) void chamfer_min_kernel(
    const float* __restrict__ p, const float* __restrict__ q,
    unsigned int* __restrict__ mk)
{
    __shared__ float4 scol[CCH];           // (-2x, -2y, -2z, |q|^2)

    const int dir = blockIdx.z;            // 0: rows=p cols=q ; 1: rows=q cols=p
    const int b   = blockIdx.y;
    const int cs  = blockIdx.x * CCH;      // column chunk start
    const float4* rowBase = (const float4*)((dir == 0 ? p : q) + (size_t)b * N_ * 4);
    const float4* colBase = (const float4*)((dir == 0 ? q : p) + (size_t)b * N_ * 4);

    // Stage + preprocess this chunk's columns (1 per thread).
    {
        float4 v = colBase[cs + threadIdx.x];
        float cc = fmaf(v.y, v.y, fmaf(v.z, v.z, v.w * v.w));
        scol[threadIdx.x] = make_float4(-2.0f * v.y, -2.0f * v.z, -2.0f * v.w, cc);
    }
    __syncthreads();

    // 8 row points per thread in registers.
    float px[PPT], py[PPT], pz[PPT], mn[PPT];
#pragma unroll
    for (int t = 0; t < PPT; ++t) {
        float4 v = rowBase[t * BLOCK + threadIdx.x];
        px[t] = v.y; py[t] = v.z; pz[t] = v.w;
        mn[t] = 3.4e38f;
    }

    // Sweep the chunk: 4 broadcast ds_read_b128 feed 32 pairs (112 VALU).
    for (int m = 0; m < CCH; m += 4) {
        float4 c0 = scol[m + 0];
        float4 c1 = scol[m + 1];
        float4 c2 = scol[m + 2];
        float4 c3 = scol[m + 3];
#pragma unroll
        for (int t = 0; t < PPT; ++t) {
            float v0 = fmaf(c0.x, px[t], fmaf(c0.y, py[t], fmaf(c0.z, pz[t], c0.w)));
            float v1 = fmaf(c1.x, px[t], fmaf(c1.y, py[t], fmaf(c1.z, pz[t], c1.w)));
            float v2 = fmaf(c2.x, px[t], fmaf(c2.y, py[t], fmaf(c2.z, pz[t], c2.w)));
            float v3 = fmaf(c3.x, px[t], fmaf(c3.y, py[t], fmaf(c3.z, pz[t], c3.w)));
            mn[t] = fminf(mn[t], fminf(v0, v1));   // v_min3_f32
            mn[t] = fminf(mn[t], fminf(v2, v3));   // v_min3_f32
        }
    }

    // Combine across chunks: exact, order-independent.
    unsigned int* row = mk + ((size_t)b * 2 + dir) * N_;
#pragma unroll
    for (int t = 0; t < PPT; ++t)
        atomicMin(&row[t * BLOCK + threadIdx.x], fkey(mn[t]));
}

__global__ __launch_bounds__(BLOCK) void chamfer_finish_kernel(
    const float* __restrict__ p, const float* __restrict__ q,
    const unsigned int* __restrict__ mk, float* __restrict__ out)
{
    const int idx  = blockIdx.x * BLOCK + threadIdx.x;   // 0..65535
    const int base = idx * 4;                            // element index into [B*2*N)
    const int n    = base & (N_ - 1);
    const int bd   = base / N_;
    const int dir  = bd & 1;
    const int b    = bd >> 1;
    const float4* rows = (const float4*)((dir == 0 ? p : q) + (size_t)b * N_ * 4);

    uint4 k4 = *(const uint4*)&mk[base];
    unsigned int ks[4] = {k4.x, k4.y, k4.z, k4.w};
    float local = 0.0f;
#pragma unroll
    for (int j = 0; j < 4; ++j) {
        float val = funkey(ks[j]);
        float4 v = rows[n + j];
        float r = fmaf(v.y, v.y, fmaf(v.z, v.z, v.w * v.w));
        float dsq = fmaxf(r + val, 0.0f) + 1e-16f;
        local += sqrtf(dsq);
    }

    for (int off = 32; off > 0; off >>= 1)
        local += __shfl_down(local, off, 64);

    __shared__ float wsum[BLOCK / 64];
    if ((threadIdx.x & 63) == 0) wsum[threadIdx.x >> 6] = local;
    __syncthreads();
    if (threadIdx.x == 0) {
        float s = 0.0f;
#pragma unroll
        for (int w = 0; w < BLOCK / 64; ++w) s += wsum[w];
        atomicAdd(out, 0.5f * s);
    }
}

extern "C" void kernel_launch(void* const* d_in, const int* in_sizes, int n_in,
                              void* d_out, int out_size, void* d_ws, size_t ws_size,
                              hipStream_t stream) {
    const float* p = (const float*)d_in[0];
    const float* q = (const float*)d_in[1];
    float* out = (float*)d_out;
    unsigned int* mk = (unsigned int*)d_ws;          // B*2*N u32 keys = 1 MB

    hipMemsetAsync(mk, 0xFF, (size_t)B_ * 2 * N_ * sizeof(unsigned int), stream);
    hipMemsetAsync(out, 0, sizeof(float), stream);

    dim3 grid1(S_, B_, 2);                           // 1024 blocks
    chamfer_min_kernel<<<grid1, BLOCK, 0, stream>>>(p, q, mk);

    dim3 grid2((B_ * 2 * N_ / 4) / BLOCK);           // 256 blocks
    chamfer_finish_kernel<<<grid2, BLOCK, 0, stream>>>(p, q, mk, out);
}

// Round 4
// 29.786 us; speedup vs baseline: 2.9485x; 1.9709x over previous
//
#include <hip/hip_runtime.h>
#include <math.h>

// ChamferLoss via matrix cores.
// Embed points as K=8 f16 vectors:
//   A-side point a: (ax,ay,az, 1, -|a|^2/2, 0,0,0)
//   B-side point b: (bx,by,bz, -|b|^2/2, 1, 0,0,0)
// => C = A*B^T has C[i][j] = a.b - (|a|^2+|b|^2)/2 = -dist^2(a,b)/2.
// min_j dist^2 = -2 * max over rows i of ... (per column j: max over i).
// Two passes (dir 0/1) so each pass only needs the cheap per-column reduce:
//   dir 0: A=q, B=p -> for each p-point (col), min over q. dir 1: swapped.
// mfma_f32_32x32x8f16 C layout: col = lane&31; the 16 regs x 2 lane-halves
// cover all 32 rows -> reg max-tree + one xor-32 shuffle.

typedef _Float16 half4 __attribute__((ext_vector_type(4)));
typedef float floatx16 __attribute__((ext_vector_type(16)));

constexpr int B_ = 64;
constexpr int N_ = 2048;
constexpr int NT = N_ / 32;        // 64 tiles per side
constexpr int BLOCK = 512;         // 8 waves
constexpr int WPB = 8;             // waves per block
constexpr int IBLK = NT / WPB;     // 8 blocks along the col-tile axis

__global__ __launch_bounds__(BLOCK, 4) void chamfer_mfma_kernel(
    const float* __restrict__ p, const float* __restrict__ q,
    float* __restrict__ out)
{
    __shared__ half4 Aarr[NT * 64];       // 32 KB: per-tile A fragments
    __shared__ float wsum[WPB];

    const int dir = blockIdx.z;            // 0: A=q,B=p ; 1: A=p,B=q
    const int b   = blockIdx.y;
    const float4* rowsA = (const float4*)((dir == 0 ? q : p) + (size_t)b * N_ * 4);
    const float4* colsB = (const float4*)((dir == 0 ? p : q) + (size_t)b * N_ * 4);

    // Build all A-role fragments for this batch in LDS.
    // A frag layout (32x32x8f16): lane l holds A[row=l%32][k=4*(l/32)+e].
    for (int j = threadIdx.x; j < N_; j += BLOCK) {
        float4 v = rowsA[j];
        _Float16 x = (_Float16)v.y, y = (_Float16)v.z, z = (_Float16)v.w;
        float xf = (float)x, yf = (float)y, zf = (float)z;
        float sq = fmaf(xf, xf, fmaf(yf, yf, zf * zf));
        half4 lo; lo[0] = x; lo[1] = y; lo[2] = z; lo[3] = (_Float16)1.0f;
        half4 hi; hi[0] = (_Float16)(-0.5f * sq);
        hi[1] = (_Float16)0.0f; hi[2] = (_Float16)0.0f; hi[3] = (_Float16)0.0f;
        const int tile = j >> 5, r = j & 31;
        Aarr[tile * 64 + r]      = lo;     // lanes 0..31: k=0..3
        Aarr[tile * 64 + 32 + r] = hi;     // lanes 32..63: k=4..7
    }

    // B-role fragment in registers: this wave owns col-tile I.
    // B frag layout: lane l holds B[k=4*(l/32)+e][col=l%32].
    const int lane = threadIdx.x & 63;
    const int wid  = threadIdx.x >> 6;
    const int I    = blockIdx.x * WPB + wid;
    half4 bfrag;
    {
        float4 v = colsB[I * 32 + (lane & 31)];
        _Float16 x = (_Float16)v.y, y = (_Float16)v.z, z = (_Float16)v.w;
        float xf = (float)x, yf = (float)y, zf = (float)z;
        float sq = fmaf(xf, xf, fmaf(yf, yf, zf * zf));
        if (lane < 32) {
            bfrag[0] = x; bfrag[1] = y; bfrag[2] = z;
            bfrag[3] = (_Float16)(-0.5f * sq);
        } else {
            bfrag[0] = (_Float16)1.0f;
            bfrag[1] = (_Float16)0.0f; bfrag[2] = (_Float16)0.0f; bfrag[3] = (_Float16)0.0f;
        }
    }
    __syncthreads();

    floatx16 zero;
#pragma unroll
    for (int i = 0; i < 16; ++i) zero[i] = 0.0f;

    // Sweep all row-tiles; track max C per column (= -min dist^2 / 2).
    float cmx = -3.4e38f;
#pragma unroll 4
    for (int J = 0; J < NT; ++J) {
        half4 afrag = Aarr[J * 64 + lane];
        floatx16 C = __builtin_amdgcn_mfma_f32_32x32x8f16(afrag, bfrag, zero, 0, 0, 0);
        float m0 = fmaxf(fmaxf(C[0],  C[1]),  C[2]);    // v_max3 chains
        float m1 = fmaxf(fmaxf(C[3],  C[4]),  C[5]);
        float m2 = fmaxf(fmaxf(C[6],  C[7]),  C[8]);
        float m3 = fmaxf(fmaxf(C[9],  C[10]), C[11]);
        float m4 = fmaxf(fmaxf(C[12], C[13]), C[14]);
        float m5 = fmaxf(fmaxf(m0, m1), C[15]);
        float m6 = fmaxf(fmaxf(m2, m3), m4);
        cmx = fmaxf(cmx, fmaxf(m5, m6));
    }

    // Combine the two lane-halves (rows 0..15-ish vs 4..31 complement).
    cmx = fmaxf(cmx, __shfl_xor(cmx, 32, 64));

    // dist = sqrt(max(-2*cmx, 0) + 1e-16); every column is held by 2 lanes.
    float dsq = fmaxf(-2.0f * cmx, 0.0f) + 1e-16f;
    float local = sqrtf(dsq);

#pragma unroll
    for (int off = 32; off > 0; off >>= 1)
        local += __shfl_xor(local, off, 64);

    if (lane == 0) wsum[wid] = local;
    __syncthreads();
    if (threadIdx.x == 0) {
        float s = 0.0f;
#pragma unroll
        for (int w = 0; w < WPB; ++w) s += wsum[w];
        atomicAdd(out, 0.25f * s);   // 0.5 chamfer factor * 0.5 lane-dup
    }
}

extern "C" void kernel_launch(void* const* d_in, const int* in_sizes, int n_in,
                              void* d_out, int out_size, void* d_ws, size_t ws_size,
                              hipStream_t stream) {
    const float* p = (const float*)d_in[0];
    const float* q = (const float*)d_in[1];
    float* out = (float*)d_out;

    hipMemsetAsync(out, 0, sizeof(float), stream);

    dim3 grid(IBLK, B_, 2);                 // 8 x 64 x 2 = 1024 blocks
    chamfer_mfma_kernel<<<grid, BLOCK, 0, stream>>>(p, q, out);
}

// Round 5
// 28.330 us; speedup vs baseline: 3.1001x; 1.0514x over previous
//
#include <hip/hip_runtime.h>
#include <math.h>

// ChamferLoss via matrix cores, B-side register-blocked x2.
// Embedding (K=8 f16):
//   A-side a: (ax,ay,az, 1, -|a|^2/2, 0,0,0)
//   B-side b: (bx,by,bz, -|b|^2/2, 1, 0,0,0)
// => C[i][j] = a.b - (|a|^2+|b|^2)/2 = -dist^2(a,b)/2 ; min dist^2 = -2 max C.
// Each wave owns TWO col-tiles so one A-frag ds_read feeds two MFMAs.

typedef _Float16 half4 __attribute__((ext_vector_type(4)));
typedef float floatx16 __attribute__((ext_vector_type(16)));

constexpr int B_ = 64;
constexpr int N_ = 2048;
constexpr int NT = N_ / 32;        // 64 tiles per side
constexpr int BLOCK = 512;         // 8 waves
constexpr int WPB = 8;
constexpr int BFRAGS = 2;          // col-tiles per wave
constexpr int IBLK = NT / (WPB * BFRAGS);   // 4 blocks along col-tile axis

__global__ __launch_bounds__(BLOCK, 4) void chamfer_mfma_kernel(
    const float* __restrict__ p, const float* __restrict__ q,
    float* __restrict__ out)
{
    __shared__ half4 Aarr[NT * 64];       // 32 KB: per-tile A fragments
    __shared__ float wsum[WPB];

    const int dir = blockIdx.z;            // 0: A=q,B=p ; 1: A=p,B=q
    const int b   = blockIdx.y;
    const float4* rowsA = (const float4*)((dir == 0 ? q : p) + (size_t)b * N_ * 4);
    const float4* colsB = (const float4*)((dir == 0 ? p : q) + (size_t)b * N_ * 4);

    // Build all A-role fragments for this batch in LDS.
    // A frag layout (32x32x8f16): lane l holds A[row=l%32][k=4*(l/32)+e].
    for (int j = threadIdx.x; j < N_; j += BLOCK) {
        float4 v = rowsA[j];
        _Float16 x = (_Float16)v.y, y = (_Float16)v.z, z = (_Float16)v.w;
        float xf = (float)x, yf = (float)y, zf = (float)z;
        float sq = fmaf(xf, xf, fmaf(yf, yf, zf * zf));
        half4 lo; lo[0] = x; lo[1] = y; lo[2] = z; lo[3] = (_Float16)1.0f;
        half4 hi; hi[0] = (_Float16)(-0.5f * sq);
        hi[1] = (_Float16)0.0f; hi[2] = (_Float16)0.0f; hi[3] = (_Float16)0.0f;
        const int tile = j >> 5, r = j & 31;
        Aarr[tile * 64 + r]      = lo;     // lanes 0..31: k=0..3
        Aarr[tile * 64 + 32 + r] = hi;     // lanes 32..63: k=4..7
    }

    // Two B-role fragments per wave (col-tiles 2W and 2W+1).
    // B frag layout: lane l holds B[k=4*(l/32)+e][col=l%32].
    const int lane = threadIdx.x & 63;
    const int wid  = threadIdx.x >> 6;
    const int W    = blockIdx.x * WPB + wid;
    half4 bf[BFRAGS];
#pragma unroll
    for (int t = 0; t < BFRAGS; ++t) {
        float4 v = colsB[(W * BFRAGS + t) * 32 + (lane & 31)];
        _Float16 x = (_Float16)v.y, y = (_Float16)v.z, z = (_Float16)v.w;
        float xf = (float)x, yf = (float)y, zf = (float)z;
        float sq = fmaf(xf, xf, fmaf(yf, yf, zf * zf));
        if (lane < 32) {
            bf[t][0] = x; bf[t][1] = y; bf[t][2] = z;
            bf[t][3] = (_Float16)(-0.5f * sq);
        } else {
            bf[t][0] = (_Float16)1.0f;
            bf[t][1] = (_Float16)0.0f; bf[t][2] = (_Float16)0.0f; bf[t][3] = (_Float16)0.0f;
        }
    }
    __syncthreads();

    floatx16 zero;
#pragma unroll
    for (int i = 0; i < 16; ++i) zero[i] = 0.0f;

    // Sweep all row-tiles; one A-frag read feeds BFRAGS MFMAs.
    float cmx0 = -3.4e38f, cmx1 = -3.4e38f;
#pragma unroll 4
    for (int J = 0; J < NT; ++J) {
        half4 afrag = Aarr[J * 64 + lane];
        floatx16 C0 = __builtin_amdgcn_mfma_f32_32x32x8f16(afrag, bf[0], zero, 0, 0, 0);
        floatx16 C1 = __builtin_amdgcn_mfma_f32_32x32x8f16(afrag, bf[1], zero, 0, 0, 0);
        {
            float m0 = fmaxf(fmaxf(C0[0],  C0[1]),  C0[2]);
            float m1 = fmaxf(fmaxf(C0[3],  C0[4]),  C0[5]);
            float m2 = fmaxf(fmaxf(C0[6],  C0[7]),  C0[8]);
            float m3 = fmaxf(fmaxf(C0[9],  C0[10]), C0[11]);
            float m4 = fmaxf(fmaxf(C0[12], C0[13]), C0[14]);
            float m5 = fmaxf(fmaxf(m0, m1), C0[15]);
            float m6 = fmaxf(fmaxf(m2, m3), m4);
            cmx0 = fmaxf(cmx0, fmaxf(m5, m6));
        }
        {
            float m0 = fmaxf(fmaxf(C1[0],  C1[1]),  C1[2]);
            float m1 = fmaxf(fmaxf(C1[3],  C1[4]),  C1[5]);
            float m2 = fmaxf(fmaxf(C1[6],  C1[7]),  C1[8]);
            float m3 = fmaxf(fmaxf(C1[9],  C1[10]), C1[11]);
            float m4 = fmaxf(fmaxf(C1[12], C1[13]), C1[14]);
            float m5 = fmaxf(fmaxf(m0, m1), C1[15]);
            float m6 = fmaxf(fmaxf(m2, m3), m4);
            cmx1 = fmaxf(cmx1, fmaxf(m5, m6));
        }
    }

    // Combine the two lane-halves; each column then held by 2 lanes.
    cmx0 = fmaxf(cmx0, __shfl_xor(cmx0, 32, 64));
    cmx1 = fmaxf(cmx1, __shfl_xor(cmx1, 32, 64));

    float local = sqrtf(fmaxf(-2.0f * cmx0, 0.0f) + 1e-16f)
                + sqrtf(fmaxf(-2.0f * cmx1, 0.0f) + 1e-16f);

#pragma unroll
    for (int off = 32; off > 0; off >>= 1)
        local += __shfl_xor(local, off, 64);

    if (lane == 0) wsum[wid] = local;
    __syncthreads();
    if (threadIdx.x == 0) {
        float s = 0.0f;
#pragma unroll
        for (int w = 0; w < WPB; ++w) s += wsum[w];
        atomicAdd(out, 0.25f * s);   // 0.5 chamfer factor * 0.5 lane-dup
    }
}

extern "C" void kernel_launch(void* const* d_in, const int* in_sizes, int n_in,
                              void* d_out, int out_size, void* d_ws, size_t ws_size,
                              hipStream_t stream) {
    const float* p = (const float*)d_in[0];
    const float* q = (const float*)d_in[1];
    float* out = (float*)d_out;

    hipMemsetAsync(out, 0, sizeof(float), stream);

    dim3 grid(IBLK, B_, 2);                 // 4 x 64 x 2 = 512 blocks
    chamfer_mfma_kernel<<<grid, BLOCK, 0, stream>>>(p, q, out);
}